// Round 9
// baseline (417.284 us; speedup 1.0000x reference)
//
#include <hip/hip_runtime.h>
#include <hip/hip_bf16.h>
#include <stdint.h>
#include <stddef.h>

// MoBA forward, MI355X.
//  prep: transpose-cast W's (4x) UNION split hs -> bf16 hi/lo UNION hsmean
//  qkvkg MEGA: GEMM1 (qkv, GLDS-staged 128^2) blocks 0..767  UNION
//              kg partial (hsm @ Wk fp32, 512 latency-hiding blocks) 768..1279
//  kg_reduce64 -> wgk_vtrans: wg_k v2 (LDS-staged, fused hi/lo out) UNION vtrans
//  gate GEMM v2: virtual-K 6144 split 8 ways (K=768/slice) -> 512 blocks (2/CU)
//  gate_topk: sums 8 partial planes, rank-based top-8 -> 32-bit block mask
//  attn v7: SINGLE-buffered K/V (41.3 KB LDS -> 3 WG/CU), stage->sync->compute,
//    XOR swizzle, bf16 P, lacc ones-MFMA, defer-max, balanced qb pairing,
//    per-WAVE block skip, fma-folded mask, guard-free exp.
//  GEMM2: o @ Wo on 128^2 tiles (GLDS-staged) -> d_out fp32
//  Aliases: kg_part = vt+obuf (dead until wgk_vtrans/attn; consumed by reduce64
//  first); gate planes 0..5 = wqkvT (dead after qkvkg); planes 6..7 = obuf
//  (dead until attn; topk reads them first). vtrans runs BEFORE gate gemm.

using bh = __bf16;
typedef __bf16 bhx8 __attribute__((ext_vector_type(8)));
typedef __bf16 bhx4 __attribute__((ext_vector_type(4)));
typedef float  f32x4 __attribute__((ext_vector_type(4)));

#define SEQ   2048
#define HIDN  2048
#define NHEAD 16
#define HDIM  128
#define NBLK  32
#define BLKSZ 64
#define NQKV  6144
#define NGATE 512   // NBLK*NHEAD gate columns
#define LDC   136   // C-tile epilogue stride: 272 B/row = 16B-aligned, 2-way banks (free)
#define PSTRIDE ((size_t)SEQ * NGATE)   // gate partial plane stride (floats)

// global -> LDS direct copy, 16 B per lane; LDS dest = wave-uniform base + lane*16
#define GLDS16(gsrc, ldst)                                                     \
  __builtin_amdgcn_global_load_lds(                                            \
      (const __attribute__((address_space(1))) uint32_t*)(gsrc),               \
      (__attribute__((address_space(3))) uint32_t*)(ldst), 16, 0, 0)

// ---------------- prep: transpose_cast4 (0..16383) U split_f32 (16384..20479)
//                        U hsmean (20480..20735) ----------------
__global__ __launch_bounds__(256) void prep(const float* __restrict__ hs,
                                            bh* __restrict__ hs_hi, bh* __restrict__ hs_lo,
                                            const float* __restrict__ Wq, const float* __restrict__ Wk,
                                            const float* __restrict__ Wv, const float* __restrict__ Wo,
                                            bh* __restrict__ wqkvT, bh* __restrict__ woT,
                                            float* __restrict__ hsm) {
  __shared__ float tile[32][33];
  const int b = blockIdx.x;
  const int t = threadIdx.x;
  if (b < 16384) {
    // transpose + cast: in[R][C] fp32 -> out[C][R] bf16 (z = which weight)
    const int z = b >> 12;
    const int x = b & 63, y = (b >> 6) & 63;
    const float* in = (z == 0) ? Wq : (z == 1) ? Wk : (z == 2) ? Wv : Wo;
    bh* out = (z < 3) ? (wqkvT + (size_t)z * HIDN * HIDN) : woT;
    const int tx = t & 31, ty = t >> 5;
    const int c0 = x * 32, r0 = y * 32;
#pragma unroll
    for (int i = 0; i < 4; i++)
      tile[ty + i * 8][tx] = in[(size_t)(r0 + ty + i * 8) * HIDN + c0 + tx];
    __syncthreads();
#pragma unroll
    for (int i = 0; i < 4; i++)
      out[(size_t)(c0 + ty + i * 8) * HIDN + r0 + tx] = (bh)tile[tx][ty + i * 8];
  } else if (b < 16384 + 4096) {
    // split fp32 -> bf16 hi + lo
    int i = ((b - 16384) * 256 + t) * 4;
    float4 v = *(const float4*)(hs + i);
    bhx4 h4, l4;
    float vv[4] = {v.x, v.y, v.z, v.w};
#pragma unroll
    for (int e = 0; e < 4; e++) {
      bh h = (bh)vv[e];
      h4[e] = h;
      l4[e] = (bh)(vv[e] - (float)h);
    }
    *(bhx4*)(hs_hi + i) = h4;
    *(bhx4*)(hs_lo + i) = l4;
  } else {
    // hsmean: block-mean of hs fp32 -> [NBLK][HIDN]
    int idx = (b - 20480) * 256 + t;          // 65536
    int n = idx >> 11, c = idx & 2047;
    const float* p = hs + (size_t)(n * BLKSZ) * HIDN + c;
    float s = 0.f;
#pragma unroll 8
    for (int r = 0; r < BLKSZ; r++) s += p[(size_t)r * HIDN];
    hsm[idx] = s * (1.0f / 64.0f);
  }
}

// ======== shared GEMM staging: 128x128 tile, BK=64, global_load_lds ========
// LDS linear [128][64] bf16 per tile; XOR swizzle (byte ^= (row&7)<<4) applied to
// the GLOBAL source at stage time and to the ds_read byte offset (both-sides rule).
#define GEMM_STAGE_TILE(SRC, r0_, ldsbase)                                       \
  {                                                                              \
    _Pragma("unroll")                                                            \
    for (int it_ = 0; it_ < 4; it_++) {                                          \
      int idx_ = it_ * 256 + t;                                                  \
      int row_ = idx_ >> 3, x_ = (idx_ & 7) << 4;                                \
      GLDS16((const char*)(SRC) + (size_t)(r0_ + row_) * strideB + kbyte +       \
                 (x_ ^ ((row_ & 7) << 4)),                                       \
             (char*)(ldsbase) + ((idx_ >> 6) << 10));                            \
    }                                                                            \
  }

// ---------------- MEGA: qkv GEMM (blocks 0..767) UNION kg partial (768..1279) ----------------
__global__ __launch_bounds__(256) void qkvkg(const bh* __restrict__ A, const bh* __restrict__ BT,
                                             bh* __restrict__ Cb,
                                             const float* __restrict__ hsm,
                                             const float* __restrict__ Wk,
                                             float* __restrict__ part) {
  __shared__ __align__(16) char smraw[128 * LDC * 2];   // 34816 B, union of both branches
  const int t = threadIdx.x;

  if (blockIdx.x < 768) {
    // ---- qkv GEMM tile ----
    bh* smem = (bh*)smraw;
    bh* As = smem;                 // [128][64] linear, swizzled
    bh* Bs = smem + 128 * 64;
    const int L = t & 63, w = t >> 6;
    const int wm = w & 1, wn = w >> 1;
    const int quad = L >> 4, lo = L & 15;
    const int m0 = (blockIdx.x / 48) * 128, n0 = (blockIdx.x % 48) * 128;
    const size_t strideB = (size_t)HIDN * 2;

    f32x4 acc[4][4];
#pragma unroll
    for (int i = 0; i < 4; i++)
#pragma unroll
      for (int j = 0; j < 4; j++) acc[i][j] = (f32x4){0.f, 0.f, 0.f, 0.f};

    for (int k0 = 0; k0 < HIDN; k0 += 64) {
      const size_t kbyte = (size_t)k0 * 2;
      GEMM_STAGE_TILE(A, m0, As);
      GEMM_STAGE_TILE(BT, n0, Bs);
      __syncthreads();
#pragma unroll
      for (int ks = 0; ks < 2; ks++) {
        bhx8 af[4], bf_[4];
#pragma unroll
        for (int i = 0; i < 4; i++) {
          const int row = wm * 64 + i * 16 + lo;
          af[i] = *(const bhx8*)((const char*)As + row * 128 +
                                 ((ks * 64 + quad * 16) ^ ((row & 7) << 4)));
        }
#pragma unroll
        for (int j = 0; j < 4; j++) {
          const int row = wn * 64 + j * 16 + lo;
          bf_[j] = *(const bhx8*)((const char*)Bs + row * 128 +
                                  ((ks * 64 + quad * 16) ^ ((row & 7) << 4)));
        }
#pragma unroll
        for (int i = 0; i < 4; i++)
#pragma unroll
          for (int j = 0; j < 4; j++)
            acc[i][j] = __builtin_amdgcn_mfma_f32_16x16x32_bf16(af[i], bf_[j], acc[i][j], 0, 0, 0);
      }
      __syncthreads();
    }

    // epilogue: scatter acc -> LDS C-tile, then fully-coalesced 16B global stores
    bh* Cs = smem;
#pragma unroll
    for (int i = 0; i < 4; i++)
#pragma unroll
      for (int j = 0; j < 4; j++)
#pragma unroll
        for (int r = 0; r < 4; r++)
          Cs[(wm * 64 + i * 16 + quad * 4 + r) * LDC + wn * 64 + j * 16 + lo] = (bh)acc[i][j][r];
    __syncthreads();
#pragma unroll
    for (int it = 0; it < 8; it++) {
      int idx = it * 256 + t;                 // 2048 chunks: 128 rows x 16
      int row = idx >> 4, cg = idx & 15;
      *(uint4*)(Cb + (size_t)(m0 + row) * NQKV + n0 + cg * 8) = *(const uint4*)&Cs[row * LDC + cg * 8];
    }
  } else {
    // ---- kg partial: 512 blocks (8 c-chunks x 64 k-chunks), high occupancy ----
    float (*hl)[32] = (float (*)[32])smraw;   // hsm[32 n][32 k] slice, 4 KB
    const int b2 = blockIdx.x - 768;
    const int c = (b2 & 7) * 256 + t;
    const int ky = b2 >> 3;
    const int k0 = ky * 32;
    for (int i = t; i < 32 * 32; i += 256)
      hl[i >> 5][i & 31] = hsm[(size_t)(i >> 5) * HIDN + k0 + (i & 31)];
    __syncthreads();
    float acc[32];
#pragma unroll
    for (int n = 0; n < 32; n++) acc[n] = 0.f;
#pragma unroll 2
    for (int k4 = 0; k4 < 8; k4++) {
      float w0 = Wk[(size_t)(k0 + k4 * 4 + 0) * HIDN + c];
      float w1 = Wk[(size_t)(k0 + k4 * 4 + 1) * HIDN + c];
      float w2 = Wk[(size_t)(k0 + k4 * 4 + 2) * HIDN + c];
      float w3 = Wk[(size_t)(k0 + k4 * 4 + 3) * HIDN + c];
#pragma unroll
      for (int n = 0; n < 32; n++) {
        float4 hv = *(const float4*)&hl[n][k4 * 4];
        acc[n] += hv.x * w0 + hv.y * w1 + hv.z * w2 + hv.w * w3;
      }
    }
#pragma unroll
    for (int n = 0; n < 32; n++)
      part[((size_t)ky * 32 + n) * HIDN + c] = acc[n];
  }
}

// ---------------- GEMM: 128^2 tile, fp32 out (o-projection) ----------------
__global__ __launch_bounds__(256) void gemm_bt128f(const bh* __restrict__ A, const bh* __restrict__ BT,
                                                   float* __restrict__ Cf, int M, int N, int K) {
  __shared__ __align__(16) bh smem[2 * 128 * 64];  // 32 KB
  bh* As = smem;
  bh* Bs = smem + 128 * 64;
  const int t = threadIdx.x;
  const int L = t & 63, w = t >> 6;
  const int wm = w & 1, wn = w >> 1;
  const int quad = L >> 4, lo = L & 15;
  const int m0 = blockIdx.y * 128, n0 = blockIdx.x * 128;
  const size_t strideB = (size_t)K * 2;

  f32x4 acc[4][4];
#pragma unroll
  for (int i = 0; i < 4; i++)
#pragma unroll
    for (int j = 0; j < 4; j++) acc[i][j] = (f32x4){0.f, 0.f, 0.f, 0.f};

  for (int k0 = 0; k0 < K; k0 += 64) {
    const size_t kbyte = (size_t)k0 * 2;
    GEMM_STAGE_TILE(A, m0, As);
    GEMM_STAGE_TILE(BT, n0, Bs);
    __syncthreads();
#pragma unroll
    for (int ks = 0; ks < 2; ks++) {
      bhx8 af[4], bf_[4];
#pragma unroll
      for (int i = 0; i < 4; i++) {
        const int row = wm * 64 + i * 16 + lo;
        af[i] = *(const bhx8*)((const char*)As + row * 128 +
                               ((ks * 64 + quad * 16) ^ ((row & 7) << 4)));
      }
#pragma unroll
      for (int j = 0; j < 4; j++) {
        const int row = wn * 64 + j * 16 + lo;
        bf_[j] = *(const bhx8*)((const char*)Bs + row * 128 +
                                ((ks * 64 + quad * 16) ^ ((row & 7) << 4)));
      }
#pragma unroll
      for (int i = 0; i < 4; i++)
#pragma unroll
        for (int j = 0; j < 4; j++)
          acc[i][j] = __builtin_amdgcn_mfma_f32_16x16x32_bf16(af[i], bf_[j], acc[i][j], 0, 0, 0);
    }
    __syncthreads();
  }

  // fp32 stores: 16 lanes x 4 B = full 64 B sectors per quad-row (no amplification)
#pragma unroll
  for (int i = 0; i < 4; i++)
#pragma unroll
    for (int j = 0; j < 4; j++)
#pragma unroll
      for (int r = 0; r < 4; r++) {
        int row = m0 + wm * 64 + i * 16 + quad * 4 + r;
        int col = n0 + wn * 64 + j * 16 + lo;
        Cf[(size_t)row * N + col] = acc[i][j][r];
      }
}

// ---------------- gate GEMM v2: virtual K=6144 (3 phases concat), 8 slices ----------------
// vk in [0,2048): hs_hi @ wg_hi; [2048,4096): hs_lo @ wg_hi; [4096,6144): hs_hi @ wg_lo.
__global__ __launch_bounds__(256) void gemm_gate_split(const bh* __restrict__ hs_hi,
                                                       const bh* __restrict__ hs_lo,
                                                       const bh* __restrict__ wg_hi,
                                                       const bh* __restrict__ wg_lo,
                                                       float* __restrict__ part6,
                                                       float* __restrict__ part2) {
  __shared__ __align__(16) bh smem[2 * 128 * 64];  // 32 KB
  bh* As = smem;
  bh* Bs = smem + 128 * 64;
  const int t = threadIdx.x;
  const int L = t & 63, w = t >> 6;
  const int wm = w & 1, wn = w >> 1;
  const int quad = L >> 4, lo = L & 15;
  const int m0 = blockIdx.y * 128, n0 = blockIdx.x * 128;
  const int z = blockIdx.z;
  const size_t strideB = (size_t)HIDN * 2;

  f32x4 acc[4][4];
#pragma unroll
  for (int i = 0; i < 4; i++)
#pragma unroll
    for (int j = 0; j < 4; j++) acc[i][j] = (f32x4){0.f, 0.f, 0.f, 0.f};

  for (int k0 = 0; k0 < 768; k0 += 64) {
    const int vk = z * 768 + k0;
    const int ph = vk >> 11;                 // 0,1,2
    const bh* Ap = (ph == 1) ? hs_lo : hs_hi;
    const bh* Bp = (ph == 2) ? wg_lo : wg_hi;
    const size_t kbyte = (size_t)(vk & 2047) * 2;
    GEMM_STAGE_TILE(Ap, m0, As);
    GEMM_STAGE_TILE(Bp, n0, Bs);
    __syncthreads();
#pragma unroll
    for (int ks = 0; ks < 2; ks++) {
      bhx8 af[4], bf_[4];
#pragma unroll
      for (int i = 0; i < 4; i++) {
        const int row = wm * 64 + i * 16 + lo;
        af[i] = *(const bhx8*)((const char*)As + row * 128 +
                               ((ks * 64 + quad * 16) ^ ((row & 7) << 4)));
      }
#pragma unroll
      for (int j = 0; j < 4; j++) {
        const int row = wn * 64 + j * 16 + lo;
        bf_[j] = *(const bhx8*)((const char*)Bs + row * 128 +
                                ((ks * 64 + quad * 16) ^ ((row & 7) << 4)));
      }
#pragma unroll
      for (int i = 0; i < 4; i++)
#pragma unroll
        for (int j = 0; j < 4; j++)
          acc[i][j] = __builtin_amdgcn_mfma_f32_16x16x32_bf16(af[i], bf_[j], acc[i][j], 0, 0, 0);
    }
    __syncthreads();
  }

  float* outp = (z < 6) ? (part6 + (size_t)z * PSTRIDE) : (part2 + (size_t)(z - 6) * PSTRIDE);
#pragma unroll
  for (int i = 0; i < 4; i++)
#pragma unroll
    for (int j = 0; j < 4; j++)
#pragma unroll
      for (int r = 0; r < 4; r++) {
        int row = m0 + wm * 64 + i * 16 + quad * 4 + r;
        int col = n0 + wn * 64 + j * 16 + lo;
        outp[(size_t)row * NGATE + col] = acc[i][j][r];
      }
}

__global__ __launch_bounds__(256) void kg_reduce64(const float* __restrict__ part, float* __restrict__ kg) {
  int idx = blockIdx.x * 256 + threadIdx.x;   // 65536
  float s = 0.f;
#pragma unroll
  for (int kc = 0; kc < 64; kc++) s += part[(size_t)kc * 65536 + idx];
  kg[idx] = s;
}

// ---------------- wgk_vtrans: vtrans (0..4095) UNION wg_k v2 (4096..4223) ----------------
__global__ __launch_bounds__(256) void wgk_vtrans(const float* __restrict__ Wq,
                                                  const float* __restrict__ kg,
                                                  bh* __restrict__ wg_hi, bh* __restrict__ wg_lo,
                                                  const bh* __restrict__ qkv, bh* __restrict__ vt) {
  __shared__ __align__(16) char smraw[49792];
  const int b = blockIdx.x;
  const int t = threadIdx.x;
  if (b < 4096) {
    // ---- vtrans: vt[h][d][s] = V^T per head ----
    float (*tile)[33] = (float (*)[33])smraw;   // 4224 B
    const int tx = t & 31, ty = t >> 5;
    const int s0 = (b & 63) * 32, d0 = ((b >> 6) & 3) * 32, h = b >> 8;
#pragma unroll
    for (int i = 0; i < 4; i++)
      tile[ty + i * 8][tx] = (float)qkv[(size_t)(s0 + ty + i * 8) * NQKV + 2 * HIDN + h * HDIM + d0 + tx];
    __syncthreads();
#pragma unroll
    for (int i = 0; i < 4; i++)
      vt[((size_t)h * HDIM + d0 + ty + i * 8) * SEQ + s0 + tx] = (bh)tile[tx][ty + i * 8];
  } else {
    // ---- wg_k v2: LDS-staged coalesced, fused bf16 hi/lo output ----
    float (*wst)[65] = (float (*)[65])smraw;               // 128x65 fp32 = 33280 B
    float (*kl)[129] = (float (*)[129])(smraw + 33280);    // 32x129 fp32 = 16512 B
    const int b2 = b - 4096;
    const int h = b2 >> 3;
    const int r0 = (b2 & 7) * 256;
    const int rloc = t & 63, ng = t >> 6;      // 4 n-groups of 8

    for (int i = t; i < 32 * 128; i += 256)
      kl[i >> 7][i & 127] = kg[(size_t)(i >> 7) * HIDN + h * HDIM + (i & 127)];

#pragma unroll
    for (int rt = 0; rt < 4; rt++) {
      __syncthreads();                          // protect wst from prior tile's readers
      for (int i = t; i < 64 * 128; i += 256) {
        int row = i >> 7, col = i & 127;        // coalesced global read, conflict-free LDS write
        wst[col][row] = Wq[(size_t)(r0 + rt * 64 + row) * HIDN + h * HDIM + col];
      }
      __syncthreads();
      float acc8[8];
#pragma unroll
      for (int nn = 0; nn < 8; nn++) acc8[nn] = 0.f;
      for (int d = 0; d < 128; d++) {
        float wv = wst[d][rloc];                // lanes consecutive -> conflict-free
#pragma unroll
        for (int nn = 0; nn < 8; nn++)
          acc8[nn] += wv * kl[ng * 8 + nn][d];  // broadcast within 16-lane group
      }
#pragma unroll
      for (int nn = 0; nn < 8; nn++) {
        int n = ng * 8 + nn;
        float v = acc8[nn];
        bh hi = (bh)v;
        size_t off = (size_t)(h * 32 + n) * HIDN + r0 + rt * 64 + rloc;
        wg_hi[off] = hi;
        wg_lo[off] = (bh)(v - (float)hi);
      }
    }
  }
}

// ---------------- gate + top-8 -> 32-bit block mask per (h,s) ----------------
__global__ __launch_bounds__(256) void gate_topk(const float* __restrict__ part6,
                                                 const float* __restrict__ part2,
                                                 unsigned* __restrict__ bsel) {
  int w = threadIdx.x >> 6, L = threadIdx.x & 63;
  int p = blockIdx.x * 4 + w;               // p = h*2048 + s
  int h = p >> 11, s = p & 2047;
  int qb = s >> 6;
  int n = L;
  float g = -1e30f;
  if (n == qb) g = 1e30f;
  else if (n < qb) {
    size_t off = (size_t)s * NGATE + h * 32 + n;
    g = part6[off] + part6[off + PSTRIDE] + part6[off + 2 * PSTRIDE] +
        part6[off + 3 * PSTRIDE] + part6[off + 4 * PSTRIDE] + part6[off + 5 * PSTRIDE] +
        part2[off] + part2[off + PSTRIDE];
  }
  int rank = 0;
#pragma unroll
  for (int j = 0; j < 32; j++) {
    float gj = __shfl(g, j, 64);
    if (gj > g || (gj == g && j < n)) rank++;
  }
  bool sel = (n <= qb) && (n < 32) && (rank < 8);
  unsigned long long bm = __ballot(sel);
  if (L == 0) bsel[p] = (unsigned)(bm & 0xffffffffull);
}

// ---------------- attn v7: 1 WG (4 waves) per (h, 64-row q-block), 3 WG/CU ----------------
// SINGLE-buffered K/V (41.3 KB LDS): stage -> __syncthreads (drains vmcnt) ->
// compute -> __syncthreads. Latency hidden by 3 co-resident WGs per CU.
__global__ __launch_bounds__(256) void attn(const bh* __restrict__ qkv, const bh* __restrict__ vt,
                                            const unsigned* __restrict__ bsel, bh* __restrict__ obuf) {
  __shared__ __align__(16) bh Ksm[64 * 128];      // 16 KB, linear 256 B rows, XOR-swizzled
  __shared__ __align__(16) bh Vsm[128 * 64];      // 16 KB, linear 128 B rows, XOR-swizzled
  __shared__ __align__(16) bh PLb[4][16 * 72];    // bf16 P, 144 B rows
  __shared__ unsigned ublk;
  const int t = threadIdx.x;
  const int w = t >> 6, L = t & 63;
  const int quad = L >> 4, lo = L & 15;
  // XCD-aware remap: bid&7 = XCD -> 2 heads per XCD (K/V ~2MB fits 4MB L2).
  // Balanced pairing: jj<32 heavy (qb 31..16, dispatched first), jj>=32 light.
  const int bid = blockIdx.x;
  const int jj = bid >> 3;
  const int h = ((bid & 7) << 1) | (jj & 1);
  const int qb = (jj < 32) ? (31 - (jj >> 1)) : ((jj - 32) >> 1);
  const int s0 = qb * 64 + w * 16;

  unsigned bs[4];
#pragma unroll
  for (int r = 0; r < 4; r++) bs[r] = bsel[h * SEQ + s0 + quad * 4 + r];
  unsigned uni = bs[0] | bs[1] | bs[2] | bs[3];
  uni |= (unsigned)__shfl_xor((int)uni, 16);
  uni |= (unsigned)__shfl_xor((int)uni, 32);
  const unsigned uniw = uni;                 // this wave's 16-row union
  if (t == 0) ublk = 0;
  __syncthreads();
  if (L == 0) atomicOr(&ublk, uni);
  __syncthreads();
  const unsigned un = ublk;                  // WG-level union (drives staging loop)

  bhx8 aq[4];
  const bh* qrow = qkv + (size_t)(s0 + lo) * NQKV + h * HDIM;
#pragma unroll
  for (int ks = 0; ks < 4; ks++) aq[ks] = *(const bhx8*)(qrow + ks * 32 + quad * 8);

  f32x4 oacc[8];
#pragma unroll
  for (int j = 0; j < 8; j++) oacc[j] = (f32x4){0.f, 0.f, 0.f, 0.f};
  f32x4 lacc = (f32x4){0.f, 0.f, 0.f, 0.f};       // row-sum accumulator (== li)
  float mi[4] = {-1e30f, -1e30f, -1e30f, -1e30f};

  bhx8 ones8;
#pragma unroll
  for (int e = 0; e < 8; e++) ones8[e] = (bh)1.0f;

  const float scale = 0.08838834764831845f;  // 1/sqrt(128)

  unsigned rem = un;                          // un != 0 (self block always set)
  while (rem) {
    const int ncur = (int)__builtin_ctz(rem);
    rem &= rem - 1;

    // stage K tile (64 rows x 256 B) + V tile (128 rows x 128 B) for block ncur.
    {
      const char* ksrc = (const char*)(qkv + (size_t)(ncur * BLKSZ) * NQKV + HIDN + h * HDIM);
      const char* vsrc = (const char*)(vt + ((size_t)h * HDIM) * SEQ + ncur * BLKSZ);
#pragma unroll
      for (int it = 0; it < 4; it++) {
        int idx = it * 256 + t;               // 1024 chunks of 16 B: row = idx>>4
        int row = idx >> 4, x = (idx & 15) << 4;
        GLDS16(ksrc + (size_t)row * (NQKV * 2) + (x ^ ((row & 7) << 4)),
               (char*)Ksm + ((idx >> 6) << 10));   // wave-uniform base; HW adds lane*16
      }
#pragma unroll
      for (int it = 0; it < 4; it++) {
        int idx = it * 256 + t;               // 1024 chunks of 16 B: row = idx>>3
        int row = idx >> 3, x = (idx & 7) << 4;
        GLDS16(vsrc + (size_t)row * (SEQ * 2) + (x ^ ((row & 7) << 4)),
               (char*)Vsm + ((idx >> 6) << 10));
      }
    }
    __syncthreads();   // drains vmcnt(0); tile ready

    // per-wave skip: none of this wave's 16 rows selected block ncur ->
    // its contribution is all-masked zeros; skip compute, keep barriers.
    if ((uniw >> ncur) & 1) {
      const char* Kc = (const char*)Ksm;
      const char* Vc = (const char*)Vsm;
      const bool self = (ncur == qb);

      f32x4 sc[4];
      __builtin_amdgcn_s_setprio(1);
#pragma unroll
      for (int nt = 0; nt < 4; nt++) {
        f32x4 s4 = (f32x4){0.f, 0.f, 0.f, 0.f};
#pragma unroll
        for (int ks = 0; ks < 4; ks++) {
          const int row = nt * 16 + lo;
          bhx8 bk = *(const bhx8*)(Kc + row * 256 + ((ks * 64 + quad * 16) ^ ((row & 7) << 4)));
          s4 = __builtin_amdgcn_mfma_f32_16x16x32_bf16(aq[ks], bk, s4, 0, 0, 0);
        }
        sc[nt] = s4;
      }
      __builtin_amdgcn_s_setprio(0);

      if (self) {
#pragma unroll
        for (int nt = 0; nt < 4; nt++)
#pragma unroll
          for (int r = 0; r < 4; r++) {
            float v = sc[nt][r] * scale;
            int kpos = ncur * BLKSZ + nt * 16 + lo;
            int qpos = s0 + quad * 4 + r;
            bool ok = ((bs[r] >> ncur) & 1) && (kpos <= qpos);
            sc[nt][r] = ok ? v : -1e30f;
          }
      } else {
        float bias[4];
#pragma unroll
        for (int r = 0; r < 4; r++)
          bias[r] = ((bs[r] >> ncur) & 1) ? 0.f : -1e30f;
#pragma unroll
        for (int nt = 0; nt < 4; nt++)
#pragma unroll
          for (int r = 0; r < 4; r++)
            sc[nt][r] = sc[nt][r] * scale + bias[r];
      }
      float rm[4];
#pragma unroll
      for (int r = 0; r < 4; r++)
        rm[r] = fmaxf(fmaxf(sc[0][r], sc[1][r]), fmaxf(sc[2][r], sc[3][r]));
#pragma unroll
      for (int off = 1; off < 16; off <<= 1)
#pragma unroll
        for (int r = 0; r < 4; r++) rm[r] = fmaxf(rm[r], __shfl_xor(rm[r], off));

      // defer-max (T13, THR=8); rows with mi=-1e30 accumulate exp(0)=1 junk until
      // their first real block triggers exceed and alpha=0 clears oacc/lacc exactly.
      bool exceed = (rm[0] > mi[0] + 8.f) || (rm[1] > mi[1] + 8.f) ||
                    (rm[2] > mi[2] + 8.f) || (rm[3] > mi[3] + 8.f);
      if (__any(exceed)) {
        float alpha[4];
#pragma unroll
        for (int r = 0; r < 4; r++) {
          float nm = fmaxf(mi[r], rm[r]);
          alpha[r] = __expf(mi[r] - nm);
          mi[r] = nm;
        }
#pragma unroll
        for (int j = 0; j < 8; j++)
#pragma unroll
          for (int r = 0; r < 4; r++) oacc[j][r] *= alpha[r];
#pragma unroll
        for (int r = 0; r < 4; r++) lacc[r] *= alpha[r];
      }

#pragma unroll
      for (int nt = 0; nt < 4; nt++)
#pragma unroll
        for (int r = 0; r < 4; r++) {
          float pv = __expf(sc[nt][r] - mi[r]);   // masked -> exp(-1e30-mi) = 0
          PLb[w][(quad * 4 + r) * 72 + nt * 16 + lo] = (bh)pv;   // per-wave slab
        }

      __builtin_amdgcn_s_setprio(1);
#pragma unroll
      for (int kk = 0; kk < 2; kk++) {
        bhx8 pa = *(const bhx8*)&PLb[w][lo * 72 + kk * 32 + quad * 8];
        // all-ones B: every output column = row-sum of P -> lacc tracks li for free
        lacc = __builtin_amdgcn_mfma_f32_16x16x32_bf16(pa, ones8, lacc, 0, 0, 0);
#pragma unroll
        for (int j = 0; j < 8; j++) {
          const int row = j * 16 + lo;
          bhx8 vv = *(const bhx8*)(Vc + row * 128 + ((kk * 64 + quad * 16) ^ ((row & 7) << 4)));
          oacc[j] = __builtin_amdgcn_mfma_f32_16x16x32_bf16(pa, vv, oacc[j], 0, 0, 0);
        }
      }
      __builtin_amdgcn_s_setprio(0);
    }

    __syncthreads();   // all waves done reading Ksm/Vsm before restage
  }

#pragma unroll
  for (int j = 0; j < 8; j++)
#pragma unroll
    for (int r = 0; r < 4; r++) {
      int row = s0 + quad * 4 + r;
      int col = h * HDIM + j * 16 + lo;
      obuf[(size_t)row * HIDN + col] = (bh)(oacc[j][r] / lacc[r]);
    }
}

// ---------------- launch ----------------
extern "C" void kernel_launch(void* const* d_in, const int* in_sizes, int n_in,
                              void* d_out, int out_size, void* d_ws, size_t ws_size,
                              hipStream_t stream) {
  const float* hs = (const float*)d_in[0];
  const float* Wq = (const float*)d_in[1];
  const float* Wk = (const float*)d_in[2];
  const float* Wv = (const float*)d_in[3];
  const float* Wo = (const float*)d_in[4];

  char* ws = (char*)d_ws;
  bh* hs_hi = (bh*)ws;            ws += (size_t)SEQ * HIDN * 2;         // 8 MB
  bh* hs_lo = (bh*)ws;            ws += (size_t)SEQ * HIDN * 2;         // 8 MB
  bh* wqkvT = (bh*)ws;            ws += (size_t)NQKV * HIDN * 2;        // 24 MB
  bh* woT = (bh*)ws;              ws += (size_t)HIDN * HIDN * 2;        // 8 MB
  bh* qkv = (bh*)ws;              ws += (size_t)SEQ * NQKV * 2;         // 24 MB
  bh* vt = (bh*)ws;               ws += (size_t)NHEAD * HDIM * SEQ * 2; // 8 MB
  bh* obuf = (bh*)ws;             ws += (size_t)SEQ * HIDN * 2;         // 8 MB
  float* hsm = (float*)ws;        ws += (size_t)NBLK * HIDN * 4;        // 256 KB
  float* kg = (float*)ws;         ws += (size_t)NBLK * HIDN * 4;        // 256 KB
  bh* wg_hi = (bh*)ws;            ws += (size_t)NGATE * HIDN * 2;       // 2 MB
  bh* wg_lo = (bh*)ws;            ws += (size_t)NGATE * HIDN * 2;       // 2 MB
  unsigned* bsel = (unsigned*)ws; ws += (size_t)NHEAD * SEQ * 4;        // 128 KB
  // Total explicit: 92.6 MB.
  // Aliases (stream-serialized liveness, new launch order):
  //  - kg_part (16 MB) = vt+obuf: consumed by kg_reduce64 BEFORE wgk_vtrans
  //    writes vt and before gate gemm writes gpart2 (= obuf).
  //  - gate planes 0..5 (24 MB) = wqkvT: dead after qkvkg GEMM.
  //  - gate planes 6..7 (8 MB) = obuf: topk reads them; attn overwrites after.
  float* kg_part = (float*)vt;
  float* gpart6 = (float*)wqkvT;
  float* gpart2 = (float*)obuf;

  // fused preprocessing: weight transposes + hs split + block means
  prep<<<16384 + 4096 + 256, 256, 0, stream>>>(hs, hs_hi, hs_lo, Wq, Wk, Wv, Wo, wqkvT, woT, hsm);

  // MEGA: qkv GEMM (768 blocks) + kg partial (512 blocks) co-resident
  qkvkg<<<768 + 512, 256, 0, stream>>>(hs_hi, wqkvT, qkv, hsm, Wk, kg_part);

  // gate path; vtrans fused alongside wg_k (vt dead until here, qkv ready)
  kg_reduce64<<<(NBLK * HIDN) / 256, 256, 0, stream>>>(kg_part, kg);
  wgk_vtrans<<<4096 + 128, 256, 0, stream>>>(Wq, kg, wg_hi, wg_lo, qkv, vt);
  gemm_gate_split<<<dim3(NGATE / 128, SEQ / 128, 8), 256, 0, stream>>>(
      hs_hi, hs_lo, wg_hi, wg_lo, gpart6, gpart2);
  gate_topk<<<(NHEAD * SEQ) / 4, 256, 0, stream>>>(gpart6, gpart2, bsel);

  // attention (1D grid, XCD-aware remap inside the kernel)
  attn<<<dim3(NBLK * NHEAD), 256, 0, stream>>>(qkv, vt, bsel, obuf);

  // output projection (128x128 tiles -> 256 blocks)
  gemm_bt128f<<<dim3(HIDN / 128, SEQ / 128), 256, 0, stream>>>(obuf, woT, (float*)d_out, SEQ, HIDN, HIDN);
}

// Round 10
// 409.837 us; speedup vs baseline: 1.0182x; 1.0182x over previous
//
#include <hip/hip_runtime.h>
#include <hip/hip_bf16.h>
#include <stdint.h>
#include <stddef.h>

// MoBA forward, MI355X.
//  prep: transpose-cast W's (4x) UNION split hs -> bf16 hi/lo UNION hsmean
//  qkvkg MEGA: GEMM1 (qkv, GLDS-staged 128^2) blocks 0..767  UNION
//              kg partial (hsm @ Wk fp32, 512 latency-hiding blocks) 768..1279
//  kg_reduce64 -> wgk_vtrans: wg_k v2 (gate cols relabeled n*16+h) UNION vtrans
//  gate GEMM v3: virtual-K 6144 / 8 slices + TRIANGULAR tile skip (40/64 tiles)
//  gate_topk: sums 8 partial planes (col n*16+h), top-8 -> 32-bit block mask
//  attn v8: SPLIT-KV flash-decode. qb<16 -> 1 WG; qb>=16 -> 2 WGs (windows
//    [0,16) / [16,qb]) writing partials (oacc,m,l); attn_combine merges.
//    Inner loop identical to v7 (single-buffer K/V, XOR swizzle, bf16 P,
//    lacc ones-MFMA, defer-max, per-WAVE skip, guard-free exp). 768 WGs =
//    3/CU all-resident; item permutation gives constant per-CU work (33 iters).
//  GEMM2: o @ Wo on 128^2 tiles (GLDS-staged) -> d_out fp32
//  Aliases: kg_part = vt+obuf (consumed by reduce64 first); gate planes 0..5 =
//  wqkvT; planes 6..7 = obuf (topk reads before attn); pom (17MB attn partials)
//  = wqkvT (dead after topk; combine reads before nothing else touches it).

using bh = __bf16;
typedef __bf16 bhx8 __attribute__((ext_vector_type(8)));
typedef __bf16 bhx4 __attribute__((ext_vector_type(4)));
typedef float  f32x4 __attribute__((ext_vector_type(4)));

#define SEQ   2048
#define HIDN  2048
#define NHEAD 16
#define HDIM  128
#define NBLK  32
#define BLKSZ 64
#define NQKV  6144
#define NGATE 512   // NBLK*NHEAD gate columns
#define LDC   136   // C-tile epilogue stride: 272 B/row = 16B-aligned, 2-way banks (free)
#define PSTRIDE ((size_t)SEQ * NGATE)   // gate partial plane stride (floats)
#define POMSTRIDE 8320                  // attn partial slab: 64x128 oacc + 64 m + 64 l

// global -> LDS direct copy, 16 B per lane; LDS dest = wave-uniform base + lane*16
#define GLDS16(gsrc, ldst)                                                     \
  __builtin_amdgcn_global_load_lds(                                            \
      (const __attribute__((address_space(1))) uint32_t*)(gsrc),               \
      (__attribute__((address_space(3))) uint32_t*)(ldst), 16, 0, 0)

// ---------------- prep: transpose_cast4 (0..16383) U split_f32 (16384..20479)
//                        U hsmean (20480..20735) ----------------
__global__ __launch_bounds__(256) void prep(const float* __restrict__ hs,
                                            bh* __restrict__ hs_hi, bh* __restrict__ hs_lo,
                                            const float* __restrict__ Wq, const float* __restrict__ Wk,
                                            const float* __restrict__ Wv, const float* __restrict__ Wo,
                                            bh* __restrict__ wqkvT, bh* __restrict__ woT,
                                            float* __restrict__ hsm) {
  __shared__ float tile[32][33];
  const int b = blockIdx.x;
  const int t = threadIdx.x;
  if (b < 16384) {
    const int z = b >> 12;
    const int x = b & 63, y = (b >> 6) & 63;
    const float* in = (z == 0) ? Wq : (z == 1) ? Wk : (z == 2) ? Wv : Wo;
    bh* out = (z < 3) ? (wqkvT + (size_t)z * HIDN * HIDN) : woT;
    const int tx = t & 31, ty = t >> 5;
    const int c0 = x * 32, r0 = y * 32;
#pragma unroll
    for (int i = 0; i < 4; i++)
      tile[ty + i * 8][tx] = in[(size_t)(r0 + ty + i * 8) * HIDN + c0 + tx];
    __syncthreads();
#pragma unroll
    for (int i = 0; i < 4; i++)
      out[(size_t)(c0 + ty + i * 8) * HIDN + r0 + tx] = (bh)tile[tx][ty + i * 8];
  } else if (b < 16384 + 4096) {
    int i = ((b - 16384) * 256 + t) * 4;
    float4 v = *(const float4*)(hs + i);
    bhx4 h4, l4;
    float vv[4] = {v.x, v.y, v.z, v.w};
#pragma unroll
    for (int e = 0; e < 4; e++) {
      bh h = (bh)vv[e];
      h4[e] = h;
      l4[e] = (bh)(vv[e] - (float)h);
    }
    *(bhx4*)(hs_hi + i) = h4;
    *(bhx4*)(hs_lo + i) = l4;
  } else {
    int idx = (b - 20480) * 256 + t;          // 65536
    int n = idx >> 11, c = idx & 2047;
    const float* p = hs + (size_t)(n * BLKSZ) * HIDN + c;
    float s = 0.f;
#pragma unroll 8
    for (int r = 0; r < BLKSZ; r++) s += p[(size_t)r * HIDN];
    hsm[idx] = s * (1.0f / 64.0f);
  }
}

// ======== shared GEMM staging: 128x128 tile, BK=64, global_load_lds ========
#define GEMM_STAGE_TILE(SRC, r0_, ldsbase)                                       \
  {                                                                              \
    _Pragma("unroll")                                                            \
    for (int it_ = 0; it_ < 4; it_++) {                                          \
      int idx_ = it_ * 256 + t;                                                  \
      int row_ = idx_ >> 3, x_ = (idx_ & 7) << 4;                                \
      GLDS16((const char*)(SRC) + (size_t)(r0_ + row_) * strideB + kbyte +       \
                 (x_ ^ ((row_ & 7) << 4)),                                       \
             (char*)(ldsbase) + ((idx_ >> 6) << 10));                            \
    }                                                                            \
  }

// ---------------- MEGA: qkv GEMM (blocks 0..767) UNION kg partial (768..1279) ----------------
__global__ __launch_bounds__(256) void qkvkg(const bh* __restrict__ A, const bh* __restrict__ BT,
                                             bh* __restrict__ Cb,
                                             const float* __restrict__ hsm,
                                             const float* __restrict__ Wk,
                                             float* __restrict__ part) {
  __shared__ __align__(16) char smraw[128 * LDC * 2];   // 34816 B, union of both branches
  const int t = threadIdx.x;

  if (blockIdx.x < 768) {
    bh* smem = (bh*)smraw;
    bh* As = smem;                 // [128][64] linear, swizzled
    bh* Bs = smem + 128 * 64;
    const int L = t & 63, w = t >> 6;
    const int wm = w & 1, wn = w >> 1;
    const int quad = L >> 4, lo = L & 15;
    const int m0 = (blockIdx.x / 48) * 128, n0 = (blockIdx.x % 48) * 128;
    const size_t strideB = (size_t)HIDN * 2;

    f32x4 acc[4][4];
#pragma unroll
    for (int i = 0; i < 4; i++)
#pragma unroll
      for (int j = 0; j < 4; j++) acc[i][j] = (f32x4){0.f, 0.f, 0.f, 0.f};

    for (int k0 = 0; k0 < HIDN; k0 += 64) {
      const size_t kbyte = (size_t)k0 * 2;
      GEMM_STAGE_TILE(A, m0, As);
      GEMM_STAGE_TILE(BT, n0, Bs);
      __syncthreads();
#pragma unroll
      for (int ks = 0; ks < 2; ks++) {
        bhx8 af[4], bf_[4];
#pragma unroll
        for (int i = 0; i < 4; i++) {
          const int row = wm * 64 + i * 16 + lo;
          af[i] = *(const bhx8*)((const char*)As + row * 128 +
                                 ((ks * 64 + quad * 16) ^ ((row & 7) << 4)));
        }
#pragma unroll
        for (int j = 0; j < 4; j++) {
          const int row = wn * 64 + j * 16 + lo;
          bf_[j] = *(const bhx8*)((const char*)Bs + row * 128 +
                                  ((ks * 64 + quad * 16) ^ ((row & 7) << 4)));
        }
#pragma unroll
        for (int i = 0; i < 4; i++)
#pragma unroll
          for (int j = 0; j < 4; j++)
            acc[i][j] = __builtin_amdgcn_mfma_f32_16x16x32_bf16(af[i], bf_[j], acc[i][j], 0, 0, 0);
      }
      __syncthreads();
    }

    bh* Cs = smem;
#pragma unroll
    for (int i = 0; i < 4; i++)
#pragma unroll
      for (int j = 0; j < 4; j++)
#pragma unroll
        for (int r = 0; r < 4; r++)
          Cs[(wm * 64 + i * 16 + quad * 4 + r) * LDC + wn * 64 + j * 16 + lo] = (bh)acc[i][j][r];
    __syncthreads();
#pragma unroll
    for (int it = 0; it < 8; it++) {
      int idx = it * 256 + t;                 // 2048 chunks: 128 rows x 16
      int row = idx >> 4, cg = idx & 15;
      *(uint4*)(Cb + (size_t)(m0 + row) * NQKV + n0 + cg * 8) = *(const uint4*)&Cs[row * LDC + cg * 8];
    }
  } else {
    float (*hl)[32] = (float (*)[32])smraw;   // hsm[32 n][32 k] slice, 4 KB
    const int b2 = blockIdx.x - 768;
    const int c = (b2 & 7) * 256 + t;
    const int ky = b2 >> 3;
    const int k0 = ky * 32;
    for (int i = t; i < 32 * 32; i += 256)
      hl[i >> 5][i & 31] = hsm[(size_t)(i >> 5) * HIDN + k0 + (i & 31)];
    __syncthreads();
    float acc[32];
#pragma unroll
    for (int n = 0; n < 32; n++) acc[n] = 0.f;
#pragma unroll 2
    for (int k4 = 0; k4 < 8; k4++) {
      float w0 = Wk[(size_t)(k0 + k4 * 4 + 0) * HIDN + c];
      float w1 = Wk[(size_t)(k0 + k4 * 4 + 1) * HIDN + c];
      float w2 = Wk[(size_t)(k0 + k4 * 4 + 2) * HIDN + c];
      float w3 = Wk[(size_t)(k0 + k4 * 4 + 3) * HIDN + c];
#pragma unroll
      for (int n = 0; n < 32; n++) {
        float4 hv = *(const float4*)&hl[n][k4 * 4];
        acc[n] += hv.x * w0 + hv.y * w1 + hv.z * w2 + hv.w * w3;
      }
    }
#pragma unroll
    for (int n = 0; n < 32; n++)
      part[((size_t)ky * 32 + n) * HIDN + c] = acc[n];
  }
}

// ---------------- GEMM: 128^2 tile, fp32 out (o-projection) ----------------
__global__ __launch_bounds__(256) void gemm_bt128f(const bh* __restrict__ A, const bh* __restrict__ BT,
                                                   float* __restrict__ Cf, int M, int N, int K) {
  __shared__ __align__(16) bh smem[2 * 128 * 64];  // 32 KB
  bh* As = smem;
  bh* Bs = smem + 128 * 64;
  const int t = threadIdx.x;
  const int L = t & 63, w = t >> 6;
  const int wm = w & 1, wn = w >> 1;
  const int quad = L >> 4, lo = L & 15;
  const int m0 = blockIdx.y * 128, n0 = blockIdx.x * 128;
  const size_t strideB = (size_t)K * 2;

  f32x4 acc[4][4];
#pragma unroll
  for (int i = 0; i < 4; i++)
#pragma unroll
    for (int j = 0; j < 4; j++) acc[i][j] = (f32x4){0.f, 0.f, 0.f, 0.f};

  for (int k0 = 0; k0 < K; k0 += 64) {
    const size_t kbyte = (size_t)k0 * 2;
    GEMM_STAGE_TILE(A, m0, As);
    GEMM_STAGE_TILE(BT, n0, Bs);
    __syncthreads();
#pragma unroll
    for (int ks = 0; ks < 2; ks++) {
      bhx8 af[4], bf_[4];
#pragma unroll
      for (int i = 0; i < 4; i++) {
        const int row = wm * 64 + i * 16 + lo;
        af[i] = *(const bhx8*)((const char*)As + row * 128 +
                               ((ks * 64 + quad * 16) ^ ((row & 7) << 4)));
      }
#pragma unroll
      for (int j = 0; j < 4; j++) {
        const int row = wn * 64 + j * 16 + lo;
        bf_[j] = *(const bhx8*)((const char*)Bs + row * 128 +
                                ((ks * 64 + quad * 16) ^ ((row & 7) << 4)));
      }
#pragma unroll
      for (int i = 0; i < 4; i++)
#pragma unroll
        for (int j = 0; j < 4; j++)
          acc[i][j] = __builtin_amdgcn_mfma_f32_16x16x32_bf16(af[i], bf_[j], acc[i][j], 0, 0, 0);
    }
    __syncthreads();
  }

#pragma unroll
  for (int i = 0; i < 4; i++)
#pragma unroll
    for (int j = 0; j < 4; j++)
#pragma unroll
      for (int r = 0; r < 4; r++) {
        int row = m0 + wm * 64 + i * 16 + quad * 4 + r;
        int col = n0 + wn * 64 + j * 16 + lo;
        Cf[(size_t)row * N + col] = acc[i][j][r];
      }
}

// ---------------- gate GEMM v3: virtual K=6144, 8 slices, TRIANGULAR skip ----------------
// Gate cols relabeled: col = n*16 + h. Tile (m,c) needed iff 8c <= 2m+1 -> 40 tiles.
__global__ __launch_bounds__(256) void gemm_gate_split(const bh* __restrict__ hs_hi,
                                                       const bh* __restrict__ hs_lo,
                                                       const bh* __restrict__ wg_hi,
                                                       const bh* __restrict__ wg_lo,
                                                       float* __restrict__ part6,
                                                       float* __restrict__ part2) {
  __shared__ __align__(16) bh smem[2 * 128 * 64];  // 32 KB
  bh* As = smem;
  bh* Bs = smem + 128 * 64;
  const int t = threadIdx.x;
  const int L = t & 63, w = t >> 6;
  const int wm = w & 1, wn = w >> 1;
  const int quad = L >> 4, lo = L & 15;
  // triangular tile decode: c=0:m 0..15 | c=1:m 4..15 | c=2:m 8..15 | c=3:m 12..15
  const int t40 = blockIdx.x;
  int cc, mm;
  if (t40 < 16)      { cc = 0; mm = t40; }
  else if (t40 < 28) { cc = 1; mm = t40 - 12; }
  else if (t40 < 36) { cc = 2; mm = t40 - 20; }
  else               { cc = 3; mm = t40 - 24; }
  const int m0 = mm * 128, n0 = cc * 128;
  const int z = blockIdx.z;
  const size_t strideB = (size_t)HIDN * 2;

  f32x4 acc[4][4];
#pragma unroll
  for (int i = 0; i < 4; i++)
#pragma unroll
    for (int j = 0; j < 4; j++) acc[i][j] = (f32x4){0.f, 0.f, 0.f, 0.f};

  for (int k0 = 0; k0 < 768; k0 += 64) {
    const int vk = z * 768 + k0;
    const int ph = vk >> 11;                 // 0,1,2
    const bh* Ap = (ph == 1) ? hs_lo : hs_hi;
    const bh* Bp = (ph == 2) ? wg_lo : wg_hi;
    const size_t kbyte = (size_t)(vk & 2047) * 2;
    GEMM_STAGE_TILE(Ap, m0, As);
    GEMM_STAGE_TILE(Bp, n0, Bs);
    __syncthreads();
#pragma unroll
    for (int ks = 0; ks < 2; ks++) {
      bhx8 af[4], bf_[4];
#pragma unroll
      for (int i = 0; i < 4; i++) {
        const int row = wm * 64 + i * 16 + lo;
        af[i] = *(const bhx8*)((const char*)As + row * 128 +
                               ((ks * 64 + quad * 16) ^ ((row & 7) << 4)));
      }
#pragma unroll
      for (int j = 0; j < 4; j++) {
        const int row = wn * 64 + j * 16 + lo;
        bf_[j] = *(const bhx8*)((const char*)Bs + row * 128 +
                                ((ks * 64 + quad * 16) ^ ((row & 7) << 4)));
      }
#pragma unroll
      for (int i = 0; i < 4; i++)
#pragma unroll
        for (int j = 0; j < 4; j++)
          acc[i][j] = __builtin_amdgcn_mfma_f32_16x16x32_bf16(af[i], bf_[j], acc[i][j], 0, 0, 0);
    }
    __syncthreads();
  }

  float* outp = (z < 6) ? (part6 + (size_t)z * PSTRIDE) : (part2 + (size_t)(z - 6) * PSTRIDE);
#pragma unroll
  for (int i = 0; i < 4; i++)
#pragma unroll
    for (int j = 0; j < 4; j++)
#pragma unroll
      for (int r = 0; r < 4; r++) {
        int row = m0 + wm * 64 + i * 16 + quad * 4 + r;
        int col = n0 + wn * 64 + j * 16 + lo;
        outp[(size_t)row * NGATE + col] = acc[i][j][r];
      }
}

__global__ __launch_bounds__(256) void kg_reduce64(const float* __restrict__ part, float* __restrict__ kg) {
  int idx = blockIdx.x * 256 + threadIdx.x;   // 65536
  float s = 0.f;
#pragma unroll
  for (int kc = 0; kc < 64; kc++) s += part[(size_t)kc * 65536 + idx];
  kg[idx] = s;
}

// ---------------- wgk_vtrans: vtrans (0..4095) UNION wg_k v2 (4096..4223) ----------------
// wg rows relabeled: gate col = n*16 + h.
__global__ __launch_bounds__(256) void wgk_vtrans(const float* __restrict__ Wq,
                                                  const float* __restrict__ kg,
                                                  bh* __restrict__ wg_hi, bh* __restrict__ wg_lo,
                                                  const bh* __restrict__ qkv, bh* __restrict__ vt) {
  __shared__ __align__(16) char smraw[49792];
  const int b = blockIdx.x;
  const int t = threadIdx.x;
  if (b < 4096) {
    float (*tile)[33] = (float (*)[33])smraw;   // 4224 B
    const int tx = t & 31, ty = t >> 5;
    const int s0 = (b & 63) * 32, d0 = ((b >> 6) & 3) * 32, h = b >> 8;
#pragma unroll
    for (int i = 0; i < 4; i++)
      tile[ty + i * 8][tx] = (float)qkv[(size_t)(s0 + ty + i * 8) * NQKV + 2 * HIDN + h * HDIM + d0 + tx];
    __syncthreads();
#pragma unroll
    for (int i = 0; i < 4; i++)
      vt[((size_t)h * HDIM + d0 + ty + i * 8) * SEQ + s0 + tx] = (bh)tile[tx][ty + i * 8];
  } else {
    float (*wst)[65] = (float (*)[65])smraw;               // 128x65 fp32 = 33280 B
    float (*kl)[129] = (float (*)[129])(smraw + 33280);    // 32x129 fp32 = 16512 B
    const int b2 = b - 4096;
    const int h = b2 >> 3;
    const int r0 = (b2 & 7) * 256;
    const int rloc = t & 63, ng = t >> 6;      // 4 n-groups of 8

    for (int i = t; i < 32 * 128; i += 256)
      kl[i >> 7][i & 127] = kg[(size_t)(i >> 7) * HIDN + h * HDIM + (i & 127)];

#pragma unroll
    for (int rt = 0; rt < 4; rt++) {
      __syncthreads();
      for (int i = t; i < 64 * 128; i += 256) {
        int row = i >> 7, col = i & 127;
        wst[col][row] = Wq[(size_t)(r0 + rt * 64 + row) * HIDN + h * HDIM + col];
      }
      __syncthreads();
      float acc8[8];
#pragma unroll
      for (int nn = 0; nn < 8; nn++) acc8[nn] = 0.f;
      for (int d = 0; d < 128; d++) {
        float wv = wst[d][rloc];
#pragma unroll
        for (int nn = 0; nn < 8; nn++)
          acc8[nn] += wv * kl[ng * 8 + nn][d];
      }
#pragma unroll
      for (int nn = 0; nn < 8; nn++) {
        int n = ng * 8 + nn;
        float v = acc8[nn];
        bh hi = (bh)v;
        size_t off = (size_t)(n * 16 + h) * HIDN + r0 + rt * 64 + rloc;   // col = n*16+h
        wg_hi[off] = hi;
        wg_lo[off] = (bh)(v - (float)hi);
      }
    }
  }
}

// ---------------- gate + top-8 -> 32-bit block mask per (h,s) ----------------
__global__ __launch_bounds__(256) void gate_topk(const float* __restrict__ part6,
                                                 const float* __restrict__ part2,
                                                 unsigned* __restrict__ bsel) {
  int w = threadIdx.x >> 6, L = threadIdx.x & 63;
  int p = blockIdx.x * 4 + w;               // p = h*2048 + s
  int h = p >> 11, s = p & 2047;
  int qb = s >> 6;
  int n = L;
  float g = -1e30f;
  if (n == qb) g = 1e30f;
  else if (n < qb) {
    size_t off = (size_t)s * NGATE + n * 16 + h;     // col = n*16+h
    g = part6[off] + part6[off + PSTRIDE] + part6[off + 2 * PSTRIDE] +
        part6[off + 3 * PSTRIDE] + part6[off + 4 * PSTRIDE] + part6[off + 5 * PSTRIDE] +
        part2[off] + part2[off + PSTRIDE];
  }
  int rank = 0;
#pragma unroll
  for (int j = 0; j < 32; j++) {
    float gj = __shfl(g, j, 64);
    if (gj > g || (gj == g && j < n)) rank++;
  }
  bool sel = (n <= qb) && (n < 32) && (rank < 8);
  unsigned long long bm = __ballot(sel);
  if (L == 0) bsel[p] = (unsigned)(bm & 0xffffffffull);
}

// ---------------- attn v8: split-KV flash-decode, 768 WGs (3/CU) ----------------
// item decode (balanced triples: (i+1)+(16-i)+16 = 33 iters/CU):
//  actual<16: qb=actual+16, window [16,qb], part1 (split)
//  16<=actual<32: qb=actual-16 (<16), window [0,qb], direct obuf
//  actual>=32: qb=actual-16 (>=16), window [0,15], part0 (split)
__global__ __launch_bounds__(256) void attn(const bh* __restrict__ qkv, const bh* __restrict__ vt,
                                            const unsigned* __restrict__ bsel, bh* __restrict__ obuf,
                                            float* __restrict__ pom) {
  __shared__ __align__(16) bh Ksm[64 * 128];      // 16 KB, linear 256 B rows, XOR-swizzled
  __shared__ __align__(16) bh Vsm[128 * 64];      // 16 KB, linear 128 B rows, XOR-swizzled
  __shared__ __align__(16) bh PLb[4][16 * 72];    // bf16 P, 144 B rows
  __shared__ unsigned ublk;
  const int t = threadIdx.x;
  const int w = t >> 6, L = t & 63;
  const int quad = L >> 4, lo = L & 15;
  const int bid = blockIdx.x;                // 0..767; bid&7 = XCD (2 heads/XCD)
  const int jj = bid >> 3;                   // 0..95
  const int h = ((bid & 7) << 1) | (jj & 1);
  const int il = jj >> 1;                    // logical item 0..47
  const int i16 = il & 15, grp = il >> 4;
  const int actual = (grp == 0) ? i16 : (grp == 1) ? (31 - i16) : (32 + i16);
  int qb, nlo, nhi, part;
  bool split;
  if (actual < 16)      { qb = actual + 16; part = 1; nlo = 16; nhi = qb; split = true; }
  else if (actual < 32) { qb = actual - 16; part = 0; nlo = 0;  nhi = qb; split = false; }
  else                  { qb = actual - 16; part = 0; nlo = 0;  nhi = 15; split = true; }
  const unsigned wmask = ((nhi == 31) ? 0xFFFFFFFFu : ((1u << (nhi + 1)) - 1)) &
                         (0xFFFFFFFFu << nlo);
  const int s0 = qb * 64 + w * 16;

  unsigned bs[4];
#pragma unroll
  for (int r = 0; r < 4; r++) bs[r] = bsel[h * SEQ + s0 + quad * 4 + r] & wmask;
  unsigned uni = bs[0] | bs[1] | bs[2] | bs[3];
  uni |= (unsigned)__shfl_xor((int)uni, 16);
  uni |= (unsigned)__shfl_xor((int)uni, 32);
  const unsigned uniw = uni;                 // this wave's 16-row union (windowed)
  if (t == 0) ublk = 0;
  __syncthreads();
  if (L == 0) atomicOr(&ublk, uni);
  __syncthreads();
  const unsigned un = ublk;                  // WG-level union (may be 0 for part0)

  bhx8 aq[4];
  const bh* qrow = qkv + (size_t)(s0 + lo) * NQKV + h * HDIM;
#pragma unroll
  for (int ks = 0; ks < 4; ks++) aq[ks] = *(const bhx8*)(qrow + ks * 32 + quad * 8);

  f32x4 oacc[8];
#pragma unroll
  for (int j = 0; j < 8; j++) oacc[j] = (f32x4){0.f, 0.f, 0.f, 0.f};
  f32x4 lacc = (f32x4){0.f, 0.f, 0.f, 0.f};       // row-sum accumulator (== li)
  float mi[4] = {-1e30f, -1e30f, -1e30f, -1e30f};

  bhx8 ones8;
#pragma unroll
  for (int e = 0; e < 8; e++) ones8[e] = (bh)1.0f;

  const float scale = 0.08838834764831845f;  // 1/sqrt(128)

  unsigned rem = un;
  while (rem) {
    const int ncur = (int)__builtin_ctz(rem);
    rem &= rem - 1;

    // stage K tile (64 rows x 256 B) + V tile (128 rows x 128 B) for block ncur.
    {
      const char* ksrc = (const char*)(qkv + (size_t)(ncur * BLKSZ) * NQKV + HIDN + h * HDIM);
      const char* vsrc = (const char*)(vt + ((size_t)h * HDIM) * SEQ + ncur * BLKSZ);
#pragma unroll
      for (int it = 0; it < 4; it++) {
        int idx = it * 256 + t;               // 1024 chunks of 16 B: row = idx>>4
        int row = idx >> 4, x = (idx & 15) << 4;
        GLDS16(ksrc + (size_t)row * (NQKV * 2) + (x ^ ((row & 7) << 4)),
               (char*)Ksm + ((idx >> 6) << 10));
      }
#pragma unroll
      for (int it = 0; it < 4; it++) {
        int idx = it * 256 + t;               // 1024 chunks of 16 B: row = idx>>3
        int row = idx >> 3, x = (idx & 7) << 4;
        GLDS16(vsrc + (size_t)row * (SEQ * 2) + (x ^ ((row & 7) << 4)),
               (char*)Vsm + ((idx >> 6) << 10));
      }
    }
    __syncthreads();   // drains vmcnt(0); tile ready

    if ((uniw >> ncur) & 1) {
      const char* Kc = (const char*)Ksm;
      const char* Vc = (const char*)Vsm;
      const bool self = (ncur == qb);

      f32x4 sc[4];
      __builtin_amdgcn_s_setprio(1);
#pragma unroll
      for (int nt = 0; nt < 4; nt++) {
        f32x4 s4 = (f32x4){0.f, 0.f, 0.f, 0.f};
#pragma unroll
        for (int ks = 0; ks < 4; ks++) {
          const int row = nt * 16 + lo;
          bhx8 bk = *(const bhx8*)(Kc + row * 256 + ((ks * 64 + quad * 16) ^ ((row & 7) << 4)));
          s4 = __builtin_amdgcn_mfma_f32_16x16x32_bf16(aq[ks], bk, s4, 0, 0, 0);
        }
        sc[nt] = s4;
      }
      __builtin_amdgcn_s_setprio(0);

      if (self) {
#pragma unroll
        for (int nt = 0; nt < 4; nt++)
#pragma unroll
          for (int r = 0; r < 4; r++) {
            float v = sc[nt][r] * scale;
            int kpos = ncur * BLKSZ + nt * 16 + lo;
            int qpos = s0 + quad * 4 + r;
            bool ok = ((bs[r] >> ncur) & 1) && (kpos <= qpos);
            sc[nt][r] = ok ? v : -1e30f;
          }
      } else {
        float bias[4];
#pragma unroll
        for (int r = 0; r < 4; r++)
          bias[r] = ((bs[r] >> ncur) & 1) ? 0.f : -1e30f;
#pragma unroll
        for (int nt = 0; nt < 4; nt++)
#pragma unroll
          for (int r = 0; r < 4; r++)
            sc[nt][r] = sc[nt][r] * scale + bias[r];
      }
      float rm[4];
#pragma unroll
      for (int r = 0; r < 4; r++)
        rm[r] = fmaxf(fmaxf(sc[0][r], sc[1][r]), fmaxf(sc[2][r], sc[3][r]));
#pragma unroll
      for (int off = 1; off < 16; off <<= 1)
#pragma unroll
        for (int r = 0; r < 4; r++) rm[r] = fmaxf(rm[r], __shfl_xor(rm[r], off));

      // defer-max (T13, THR=8); rows with mi=-1e30 accumulate exp(0)=1 junk until
      // their first real block triggers exceed (alpha=0 clears exactly). Rows with
      // EMPTY windowed mask keep m=-1e30 forever -> zeroed in combine via alpha=0.
      bool exceed = (rm[0] > mi[0] + 8.f) || (rm[1] > mi[1] + 8.f) ||
                    (rm[2] > mi[2] + 8.f) || (rm[3] > mi[3] + 8.f);
      if (__any(exceed)) {
        float alpha[4];
#pragma unroll
        for (int r = 0; r < 4; r++) {
          float nm = fmaxf(mi[r], rm[r]);
          alpha[r] = __expf(mi[r] - nm);
          mi[r] = nm;
        }
#pragma unroll
        for (int j = 0; j < 8; j++)
#pragma unroll
          for (int r = 0; r < 4; r++) oacc[j][r] *= alpha[r];
#pragma unroll
        for (int r = 0; r < 4; r++) lacc[r] *= alpha[r];
      }

#pragma unroll
      for (int nt = 0; nt < 4; nt++)
#pragma unroll
        for (int r = 0; r < 4; r++) {
          float pv = __expf(sc[nt][r] - mi[r]);   // masked -> exp(-1e30-mi) = 0
          PLb[w][(quad * 4 + r) * 72 + nt * 16 + lo] = (bh)pv;
        }

      __builtin_amdgcn_s_setprio(1);
#pragma unroll
      for (int kk = 0; kk < 2; kk++) {
        bhx8 pa = *(const bhx8*)&PLb[w][lo * 72 + kk * 32 + quad * 8];
        lacc = __builtin_amdgcn_mfma_f32_16x16x32_bf16(pa, ones8, lacc, 0, 0, 0);
#pragma unroll
        for (int j = 0; j < 8; j++) {
          const int row = j * 16 + lo;
          bhx8 vv = *(const bhx8*)(Vc + row * 128 + ((kk * 64 + quad * 16) ^ ((row & 7) << 4)));
          oacc[j] = __builtin_amdgcn_mfma_f32_16x16x32_bf16(pa, vv, oacc[j], 0, 0, 0);
        }
      }
      __builtin_amdgcn_s_setprio(0);
    }

    __syncthreads();   // all waves done reading Ksm/Vsm before restage
  }

  if (!split) {
#pragma unroll
    for (int j = 0; j < 8; j++)
#pragma unroll
      for (int r = 0; r < 4; r++) {
        int row = s0 + quad * 4 + r;
        int col = h * HDIM + j * 16 + lo;
        obuf[(size_t)row * HIDN + col] = (bh)(oacc[j][r] / lacc[r]);
      }
  } else {
    float* slab = pom + (size_t)((h * 16 + (qb - 16)) * 2 + part) * POMSTRIDE;
    const int rl0 = w * 16 + quad * 4;
#pragma unroll
    for (int j = 0; j < 8; j++)
#pragma unroll
      for (int r = 0; r < 4; r++)
        slab[(rl0 + r) * 128 + j * 16 + lo] = oacc[j][r];
    if (lo == 0) {
#pragma unroll
      for (int r = 0; r < 4; r++) {
        slab[8192 + rl0 + r] = mi[r];
        slab[8256 + rl0 + r] = lacc[r];
      }
    }
  }
}

// ---------------- attn_combine: merge split partials -> obuf rows >= 1024 ----------------
__global__ __launch_bounds__(256) void attn_combine(const float* __restrict__ pom,
                                                    bh* __restrict__ obuf) {
  const int b = blockIdx.x;                  // 256: h*16 + qs
  const int h = b >> 4, qs = b & 15;
  const int t = threadIdx.x;
  const float* s0 = pom + (size_t)((h * 16 + qs) * 2 + 0) * POMSTRIDE;
  const float* s1 = s0 + POMSTRIDE;
  const int rl = t >> 2;                     // 0..63
  const int c0 = (t & 3) * 32;
  float m0 = s0[8192 + rl], l0 = s0[8256 + rl];
  float m1 = s1[8192 + rl], l1 = s1[8256 + rl];
  float m = fmaxf(m0, m1);
  float a0 = __expf(m0 - m), a1 = __expf(m1 - m);   // empty part -> m=-1e30 -> a=0
  float inv = 1.f / (l0 * a0 + l1 * a1);            // part1 has self -> l >= ~1
  a0 *= inv; a1 *= inv;
  const int row = (qs + 16) * 64 + rl;
  bh* orow = obuf + (size_t)row * HIDN + h * HDIM + c0;
  const float* p0 = s0 + rl * 128 + c0;
  const float* p1 = s1 + rl * 128 + c0;
#pragma unroll
  for (int c = 0; c < 32; c += 4) {
    float4 v0 = *(const float4*)(p0 + c);
    float4 v1 = *(const float4*)(p1 + c);
    bhx4 o4;
    o4[0] = (bh)(v0.x * a0 + v1.x * a1);
    o4[1] = (bh)(v0.y * a0 + v1.y * a1);
    o4[2] = (bh)(v0.z * a0 + v1.z * a1);
    o4[3] = (bh)(v0.w * a0 + v1.w * a1);
    *(bhx4*)(orow + c) = o4;
  }
}

// ---------------- launch ----------------
extern "C" void kernel_launch(void* const* d_in, const int* in_sizes, int n_in,
                              void* d_out, int out_size, void* d_ws, size_t ws_size,
                              hipStream_t stream) {
  const float* hs = (const float*)d_in[0];
  const float* Wq = (const float*)d_in[1];
  const float* Wk = (const float*)d_in[2];
  const float* Wv = (const float*)d_in[3];
  const float* Wo = (const float*)d_in[4];

  char* ws = (char*)d_ws;
  bh* hs_hi = (bh*)ws;            ws += (size_t)SEQ * HIDN * 2;         // 8 MB
  bh* hs_lo = (bh*)ws;            ws += (size_t)SEQ * HIDN * 2;         // 8 MB
  bh* wqkvT = (bh*)ws;            ws += (size_t)NQKV * HIDN * 2;        // 24 MB
  bh* woT = (bh*)ws;              ws += (size_t)HIDN * HIDN * 2;        // 8 MB
  bh* qkv = (bh*)ws;              ws += (size_t)SEQ * NQKV * 2;         // 24 MB
  bh* vt = (bh*)ws;               ws += (size_t)NHEAD * HDIM * SEQ * 2; // 8 MB
  bh* obuf = (bh*)ws;             ws += (size_t)SEQ * HIDN * 2;         // 8 MB
  float* hsm = (float*)ws;        ws += (size_t)NBLK * HIDN * 4;        // 256 KB
  float* kg = (float*)ws;         ws += (size_t)NBLK * HIDN * 4;        // 256 KB
  bh* wg_hi = (bh*)ws;            ws += (size_t)NGATE * HIDN * 2;       // 2 MB
  bh* wg_lo = (bh*)ws;            ws += (size_t)NGATE * HIDN * 2;       // 2 MB
  unsigned* bsel = (unsigned*)ws; ws += (size_t)NHEAD * SEQ * 4;        // 128 KB
  // Total explicit: 92.6 MB. Aliases (stream-serialized liveness):
  //  - kg_part (16 MB) = vt+obuf: consumed by kg_reduce64 before vt/obuf writes.
  //  - gate planes 0..5 (24 MB) = wqkvT: dead after qkvkg GEMM.
  //  - gate planes 6..7 (8 MB) = obuf: topk reads them; attn/combine write after.
  //  - pom (17 MB attn split partials) = wqkvT: gpart6 dead after topk; attn
  //    writes pom, attn_combine reads it, then wqkvT unused.
  float* kg_part = (float*)vt;
  float* gpart6 = (float*)wqkvT;
  float* gpart2 = (float*)obuf;
  float* pom = (float*)wqkvT;

  // fused preprocessing: weight transposes + hs split + block means
  prep<<<16384 + 4096 + 256, 256, 0, stream>>>(hs, hs_hi, hs_lo, Wq, Wk, Wv, Wo, wqkvT, woT, hsm);

  // MEGA: qkv GEMM (768 blocks) + kg partial (512 blocks) co-resident
  qkvkg<<<768 + 512, 256, 0, stream>>>(hs_hi, wqkvT, qkv, hsm, Wk, kg_part);

  // gate path; vtrans fused alongside wg_k
  kg_reduce64<<<(NBLK * HIDN) / 256, 256, 0, stream>>>(kg_part, kg);
  wgk_vtrans<<<4096 + 128, 256, 0, stream>>>(Wq, kg, wg_hi, wg_lo, qkv, vt);
  gemm_gate_split<<<dim3(40, 1, 8), 256, 0, stream>>>(
      hs_hi, hs_lo, wg_hi, wg_lo, gpart6, gpart2);
  gate_topk<<<(NHEAD * SEQ) / 4, 256, 0, stream>>>(gpart6, gpart2, bsel);

  // attention: split-KV (768 WGs, 3/CU) + combine for qb>=16
  attn<<<768, 256, 0, stream>>>(qkv, vt, bsel, obuf, pom);
  attn_combine<<<256, 256, 0, stream>>>(pom, obuf);

  // output projection (128x128 tiles -> 256 blocks)
  gemm_bt128f<<<dim3(HIDN / 128, SEQ / 128), 256, 0, stream>>>(obuf, woT, (float*)d_out, SEQ, HIDN, HIDN);
}